// Round 1
// baseline (1568.926 us; speedup 1.0000x reference)
//
#include <hip/hip_runtime.h>
#include <cstdint>
#include <cstddef>

#define B_ 4
#define C_ 128
#define H_ 128
#define W_ 128
#define P_ (H_*W_)       // 16384
#define NH_ 8
#define NL_ 3
#define NP_ 4
#define HD_ 16
#define C2_ 64

// ---- workspace layout (float elements) ----
#define SZ_V      ((size_t)B_*NL_*P_*C_)          // 25165824  v projected, pixel-major [b][l][p][c]
#define OFF_V     ((size_t)0)
#define OFF_HID   (OFF_V + SZ_V)                   // hid [br][b][c][p], later reused as out_pre [b][p][c]
#define SZ_HID    ((size_t)2*B_*C2_*P_)            // 8388608
#define OFF_MP    (OFF_HID + SZ_HID)               // metaP [b][h][p][24]  (px,py)*12
#define SZ_MP     ((size_t)B_*NH_*P_*24)           // 12582912
#define OFF_MA    (OFF_MP + SZ_MP)                 // metaA [b][h][p][12]  attn
#define SZ_MA     ((size_t)B_*NH_*P_*12)           // 6291456
#define OFF_ST    (OFF_MA + SZ_MA)                 // GN stats [br][b][g][2]
#define SZ_ST     ((size_t)128)
#define OFF_BE    (OFF_ST + SZ_ST)                 // vp effective bias [l][128]
#define SZ_BE     ((size_t)(NL_*C_))

// ---------------------------------------------------------------------------
// prep: zero GN stats; fold level_embed into vp bias:
// bias_eff[l][o] = vp_b[o] + sum_k vp_w[o][k]*le[l][k]
__global__ void k_prep(const float* __restrict__ vp_w, const float* __restrict__ vp_b,
                       const float* __restrict__ le, float* __restrict__ bias_eff,
                       float* __restrict__ stats)
{
    const int t = threadIdx.x;            // 384 threads
    if (t < 128) stats[t] = 0.f;
    const int l = t >> 7;                 // 0..2
    const int o = t & 127;
    float d = vp_b[o];
    for (int k = 0; k < 128; ++k) d = fmaf(vp_w[o*128 + k], le[l*128 + k], d);
    bias_eff[l*128 + o] = d;
}

// ---------------------------------------------------------------------------
// conv1 for both branches (grid.z): hid = W1*query + b1 (pre-GN), plus GN stats.
__global__ __launch_bounds__(256) void k_conv1(
    const float* __restrict__ q,
    const float* __restrict__ w_so, const float* __restrict__ b_so,
    const float* __restrict__ w_aw, const float* __restrict__ b_aw,
    float* __restrict__ hid, float* __restrict__ stats)
{
    const int tid = threadIdx.x;
    const int b = blockIdx.y, br = blockIdx.z;
    const float* __restrict__ w  = br ? w_aw : w_so;
    const float* __restrict__ bi = br ? b_aw : b_so;
    const int p = blockIdx.x*256 + tid;

    const float* qp = q + (size_t)b*C_*P_ + p;
    float qv[128];
#pragma unroll
    for (int i = 0; i < 128; ++i) qv[i] = qp[(size_t)i*P_];

    auto dot128 = [&](const float* __restrict__ wr) -> float {
        float d0=0.f,d1=0.f,d2=0.f,d3=0.f;
#pragma unroll
        for (int i = 0; i < 128; i += 4) {
            d0 = fmaf(wr[i+0], qv[i+0], d0);
            d1 = fmaf(wr[i+1], qv[i+1], d1);
            d2 = fmaf(wr[i+2], qv[i+2], d2);
            d3 = fmaf(wr[i+3], qv[i+3], d3);
        }
        return (d0+d1)+(d2+d3);
    };

    float* hp = hid + ((size_t)(br*B_ + b)*C2_)*P_ + p;
    for (int g = 0; g < 8; ++g) {           // group loop (runtime)
        float s = 0.f, ss = 0.f;
#pragma unroll
        for (int j = 0; j < 8; ++j) {
            const int oc = g*8 + j;
            float v = dot128(w + (size_t)oc*128) + bi[oc];
            hp[(size_t)oc*P_] = v;
            s += v; ss += v*v;
        }
#pragma unroll
        for (int off = 32; off > 0; off >>= 1) {
            s  += __shfl_down(s,  off, 64);
            ss += __shfl_down(ss, off, 64);
        }
        if ((tid & 63) == 0) {
            atomicAdd(&stats[((br*B_ + b)*8 + g)*2 + 0], s);
            atomicAdd(&stats[((br*B_ + b)*8 + g)*2 + 1], ss);
        }
    }
}

// ---------------------------------------------------------------------------
// conv2 + meta: GN-normalize hid, ReLU, small matvecs -> sampling coords + softmax attn
__global__ __launch_bounds__(256) void k_conv2(
    const float* __restrict__ hid, const float* __restrict__ stats,
    const float* __restrict__ so_g, const float* __restrict__ so_be,
    const float* __restrict__ aw_g, const float* __restrict__ aw_be,
    const float* __restrict__ so_w2, const float* __restrict__ so_b2,
    const float* __restrict__ aw_w2, const float* __restrict__ aw_b2,
    float* __restrict__ metaP, float* __restrict__ metaA)
{
    __shared__ float sc[2][64], sh[2][64];
    const int tid = threadIdx.x;
    const int b = blockIdx.y;
    if (tid < 128) {
        const int br = tid >> 6, c = tid & 63, g = c >> 3;
        const float ninv = 1.f/(8.f*(float)P_);
        float s  = stats[((br*B_ + b)*8 + g)*2 + 0];
        float ss = stats[((br*B_ + b)*8 + g)*2 + 1];
        float mu  = s*ninv;
        float var = ss*ninv - mu*mu;
        float rs  = rsqrtf(var + 1e-5f);
        float ga = br ? aw_g[c]  : so_g[c];
        float be = br ? aw_be[c] : so_be[c];
        sc[br][c] = ga*rs;
        sh[br][c] = be - mu*ga*rs;
    }
    __syncthreads();

    const int p = blockIdx.x*256 + tid;
    const int x = p & (W_-1), y = p >> 7;
    const float refx = (float)x * (1.f/(float)(W_-1));
    const float refy = (float)y * (1.f/(float)(H_-1));

    float h[64];
    {
        const float* hs = hid + ((size_t)(0*B_ + b)*C2_)*P_ + p;
#pragma unroll
        for (int k = 0; k < 64; ++k)
            h[k] = fmaxf(fmaf(hs[(size_t)k*P_], sc[0][k], sh[0][k]), 0.f);
    }
    // sampling-offset branch: 192 outputs -> px,py
    for (int hh = 0; hh < NH_; ++hh) {
        float2* mp = (float2*)(metaP + ((size_t)(b*NH_ + hh)*P_ + p)*24);
        for (int s = 0; s < 12; ++s) {
            const int oc = (hh*12 + s)*2;
            const float* w0 = so_w2 + (size_t)oc*64;
            const float* w1 = w0 + 64;
            float a0=0.f,a1=0.f,c0=0.f,c1=0.f;
#pragma unroll
            for (int k = 0; k < 64; k += 2) {
                a0 = fmaf(w0[k],   h[k],   a0);
                a1 = fmaf(w0[k+1], h[k+1], a1);
                c0 = fmaf(w1[k],   h[k],   c0);
                c1 = fmaf(w1[k+1], h[k+1], c1);
            }
            float ox = a0+a1 + so_b2[oc];
            float oy = c0+c1 + so_b2[oc+1];
            float lx = fminf(fmaxf(refx + ox*(1.f/(float)W_), 0.f), 1.f);
            float ly = fminf(fmaxf(refy + oy*(1.f/(float)H_), 0.f), 1.f);
            mp[s] = make_float2(lx*(float)W_ - 0.5f, ly*(float)H_ - 0.5f);
        }
    }
    // attention branch: 96 outputs -> softmax over 12 per head
    {
        const float* ha = hid + ((size_t)(1*B_ + b)*C2_)*P_ + p;
#pragma unroll
        for (int k = 0; k < 64; ++k)
            h[k] = fmaxf(fmaf(ha[(size_t)k*P_], sc[1][k], sh[1][k]), 0.f);
    }
    for (int hh = 0; hh < NH_; ++hh) {
        float a[12];
#pragma unroll
        for (int s = 0; s < 12; ++s) {
            const int oc = hh*12 + s;
            const float* wr = aw_w2 + (size_t)oc*64;
            float d0=0.f,d1=0.f;
#pragma unroll
            for (int k = 0; k < 64; k += 2) {
                d0 = fmaf(wr[k],   h[k],   d0);
                d1 = fmaf(wr[k+1], h[k+1], d1);
            }
            a[s] = d0+d1 + aw_b2[oc];
        }
        float m = a[0];
#pragma unroll
        for (int s = 1; s < 12; ++s) m = fmaxf(m, a[s]);
        float sum = 0.f;
#pragma unroll
        for (int s = 0; s < 12; ++s) { a[s] = __expf(a[s]-m); sum += a[s]; }
        const float inv = 1.f/sum;
        float* ma = metaA + ((size_t)(b*NH_ + hh)*P_ + p)*12;
#pragma unroll
        for (int s = 0; s < 12; ++s) ma[s] = a[s]*inv;
    }
}

// ---------------------------------------------------------------------------
// value projection: v[b][l][p][c] = vp_w * (values+le) + vp_b   (le folded into bias_eff)
__global__ __launch_bounds__(256) void k_vproj(
    const float* __restrict__ vals, const float* __restrict__ vp_w,
    const float* __restrict__ bias_eff, float* __restrict__ v_ws)
{
    const int tid = threadIdx.x;
    const int bl = blockIdx.y;            // b*NL + l
    const int l  = bl % NL_;
    const int p  = blockIdx.x*256 + tid;

    const float* ip = vals + (size_t)bl*C_*P_ + p;
    float qv[128];
#pragma unroll
    for (int i = 0; i < 128; ++i) qv[i] = ip[(size_t)i*P_];

    auto dot128 = [&](const float* __restrict__ wr) -> float {
        float d0=0.f,d1=0.f,d2=0.f,d3=0.f;
#pragma unroll
        for (int i = 0; i < 128; i += 4) {
            d0 = fmaf(wr[i+0], qv[i+0], d0);
            d1 = fmaf(wr[i+1], qv[i+1], d1);
            d2 = fmaf(wr[i+2], qv[i+2], d2);
            d3 = fmaf(wr[i+3], qv[i+3], d3);
        }
        return (d0+d1)+(d2+d3);
    };

    float4* op = (float4*)(v_ws + ((size_t)bl*P_ + p)*C_);
    const float* be = bias_eff + l*128;
    for (int oq = 0; oq < 32; ++oq) {
        const float* wr = vp_w + (size_t)oq*4*128;
        float4 r;
        r.x = dot128(wr)        + be[oq*4+0];
        r.y = dot128(wr + 128)  + be[oq*4+1];
        r.z = dot128(wr + 256)  + be[oq*4+2];
        r.w = dot128(wr + 384)  + be[oq*4+3];
        op[oq] = r;
    }
}

// ---------------------------------------------------------------------------
// bilinear sampling + attention-weighted sum.
// block = 256 threads = 64 (pixel,head) units x 4 lanes (4 channels each)
__global__ __launch_bounds__(256) void k_sample(
    const float* __restrict__ v_ws, const float* __restrict__ metaP,
    const float* __restrict__ metaA, float* __restrict__ out_pre)
{
    const int tid = threadIdx.x;
    const int u  = tid >> 2;              // 0..63
    const int c4 = tid & 3;               // 4 channels per lane
    const int p  = blockIdx.x*64 + u;
    const int hh = blockIdx.y, b = blockIdx.z;

    const size_t mbase = (size_t)(b*NH_ + hh)*P_ + p;
    const float4* mp4 = (const float4*)(metaP + mbase*24);
    const float4* ma4 = (const float4*)(metaA + mbase*12);

    float pxv[12], pyv[12], av[12];
#pragma unroll
    for (int i = 0; i < 6; ++i) {
        float4 m = mp4[i];
        pxv[i*2]   = m.x; pyv[i*2]   = m.y;
        pxv[i*2+1] = m.z; pyv[i*2+1] = m.w;
    }
#pragma unroll
    for (int i = 0; i < 3; ++i) {
        float4 m = ma4[i];
        av[i*4]=m.x; av[i*4+1]=m.y; av[i*4+2]=m.z; av[i*4+3]=m.w;
    }

    float ax=0.f, ay=0.f, az=0.f, aw=0.f;
#pragma unroll
    for (int l = 0; l < NL_; ++l) {
        const float4* vb = (const float4*)(v_ws + ((size_t)(b*NL_ + l)*P_)*C_ + hh*HD_ + c4*4);
        // per-pixel stride in float4 units = C_/4 = 32
#pragma unroll
        for (int pt = 0; pt < NP_; ++pt) {
            const int s = l*4 + pt;
            float px = fminf(fmaxf(pxv[s], 0.f), (float)(W_-1));
            float py = fminf(fmaxf(pyv[s], 0.f), (float)(H_-1));
            float x0f = floorf(px), y0f = floorf(py);
            float wx = px - x0f, wy = py - y0f;
            int x0 = (int)x0f, y0 = (int)y0f;
            int x1 = min(x0+1, W_-1), y1 = min(y0+1, H_-1);
            const float4* r0 = vb + (size_t)(y0*W_)*32;
            const float4* r1 = vb + (size_t)(y1*W_)*32;
            float4 v00 = r0[(size_t)x0*32], v01 = r0[(size_t)x1*32];
            float4 v10 = r1[(size_t)x0*32], v11 = r1[(size_t)x1*32];
            float tx, bx2, val;
            float a = av[s];
            tx = v00.x + (v01.x - v00.x)*wx; bx2 = v10.x + (v11.x - v10.x)*wx;
            val = tx + (bx2 - tx)*wy;  ax = fmaf(a, val, ax);
            tx = v00.y + (v01.y - v00.y)*wx; bx2 = v10.y + (v11.y - v10.y)*wx;
            val = tx + (bx2 - tx)*wy;  ay = fmaf(a, val, ay);
            tx = v00.z + (v01.z - v00.z)*wx; bx2 = v10.z + (v11.z - v10.z)*wx;
            val = tx + (bx2 - tx)*wy;  az = fmaf(a, val, az);
            tx = v00.w + (v01.w - v00.w)*wx; bx2 = v10.w + (v11.w - v10.w)*wx;
            val = tx + (bx2 - tx)*wy;  aw = fmaf(a, val, aw);
        }
    }
    float4* op = (float4*)(out_pre + ((size_t)b*P_ + p)*C_ + hh*HD_ + c4*4);
    *op = make_float4(ax, ay, az, aw);
}

// ---------------------------------------------------------------------------
// final conv: out[b][oc][p] = op_w[oc][:] . out_pre[b][p][:] + op_b[oc]
__global__ __launch_bounds__(256) void k_convout(
    const float* __restrict__ inp, const float* __restrict__ op_w,
    const float* __restrict__ op_b, float* __restrict__ out)
{
    const int tid = threadIdx.x;
    const int b = blockIdx.y;
    const int p = blockIdx.x*256 + tid;

    const float4* ip = (const float4*)(inp + ((size_t)b*P_ + p)*C_);
    float qv[128];
#pragma unroll
    for (int i = 0; i < 32; ++i) {
        float4 v = ip[i];
        qv[4*i]=v.x; qv[4*i+1]=v.y; qv[4*i+2]=v.z; qv[4*i+3]=v.w;
    }

    auto dot128 = [&](const float* __restrict__ wr) -> float {
        float d0=0.f,d1=0.f,d2=0.f,d3=0.f;
#pragma unroll
        for (int i = 0; i < 128; i += 4) {
            d0 = fmaf(wr[i+0], qv[i+0], d0);
            d1 = fmaf(wr[i+1], qv[i+1], d1);
            d2 = fmaf(wr[i+2], qv[i+2], d2);
            d3 = fmaf(wr[i+3], qv[i+3], d3);
        }
        return (d0+d1)+(d2+d3);
    };

    float* outp = out + (size_t)b*C_*P_ + p;
    for (int oc = 0; oc < 128; oc += 2) {
        float r0 = dot128(op_w + (size_t)oc*128)     + op_b[oc];
        float r1 = dot128(op_w + (size_t)(oc+1)*128) + op_b[oc+1];
        outp[(size_t)oc*P_]     = r0;
        outp[(size_t)(oc+1)*P_] = r1;
    }
}

// ---------------------------------------------------------------------------
extern "C" void kernel_launch(void* const* d_in, const int* in_sizes, int n_in,
                              void* d_out, int out_size, void* d_ws, size_t ws_size,
                              hipStream_t stream)
{
    const float* query = (const float*)d_in[0];
    // d_in[1] = keys : UNUSED by reference
    const float* values = (const float*)d_in[2];
    const float* so_w1 = (const float*)d_in[3];
    const float* so_b1 = (const float*)d_in[4];
    const float* so_g  = (const float*)d_in[5];
    const float* so_be = (const float*)d_in[6];
    const float* so_w2 = (const float*)d_in[7];
    const float* so_b2 = (const float*)d_in[8];
    const float* aw_w1 = (const float*)d_in[9];
    const float* aw_b1 = (const float*)d_in[10];
    const float* aw_g  = (const float*)d_in[11];
    const float* aw_be = (const float*)d_in[12];
    const float* aw_w2 = (const float*)d_in[13];
    const float* aw_b2 = (const float*)d_in[14];
    const float* vp_w  = (const float*)d_in[15];
    const float* vp_b  = (const float*)d_in[16];
    const float* op_w  = (const float*)d_in[17];
    const float* op_b  = (const float*)d_in[18];
    const float* le    = (const float*)d_in[19];

    float* ws      = (float*)d_ws;
    float* v_ws    = ws + OFF_V;
    float* hid     = ws + OFF_HID;
    float* metaP   = ws + OFF_MP;
    float* metaA   = ws + OFF_MA;
    float* stats   = ws + OFF_ST;
    float* be      = ws + OFF_BE;
    float* out_pre = hid;                 // hid is dead after k_conv2 -> reuse
    float* out     = (float*)d_out;

    k_prep<<<dim3(1), dim3(384), 0, stream>>>(vp_w, vp_b, le, be, stats);
    k_vproj<<<dim3(P_/256, B_*NL_), dim3(256), 0, stream>>>(values, vp_w, be, v_ws);
    k_conv1<<<dim3(P_/256, B_, 2), dim3(256), 0, stream>>>(query, so_w1, so_b1, aw_w1, aw_b1, hid, stats);
    k_conv2<<<dim3(P_/256, B_), dim3(256), 0, stream>>>(hid, stats, so_g, so_be, aw_g, aw_be,
                                                        so_w2, so_b2, aw_w2, aw_b2, metaP, metaA);
    k_sample<<<dim3(P_/64, NH_, B_), dim3(256), 0, stream>>>(v_ws, metaP, metaA, out_pre);
    k_convout<<<dim3(P_/256, B_), dim3(256), 0, stream>>>(out_pre, op_w, op_b, out);
}

// Round 2
// 616.159 us; speedup vs baseline: 2.5463x; 2.5463x over previous
//
#include <hip/hip_runtime.h>
#include <cstdint>
#include <cstddef>

#define B_ 4
#define C_ 128
#define H_ 128
#define W_ 128
#define P_ (H_*W_)       // 16384
#define NH_ 8
#define NL_ 3
#define NP_ 4
#define HD_ 16
#define C2_ 64

// ---- workspace layout (float elements) ----
#define SZ_V      ((size_t)B_*NL_*P_*C_)          // v projected, pixel-major [b][l][p][c]
#define OFF_V     ((size_t)0)
#define OFF_HID   (OFF_V + SZ_V)                   // hid [br][b][c][p], later reused as out_pre [b][p][c]
#define SZ_HID    ((size_t)2*B_*C2_*P_)
#define OFF_MP    (OFF_HID + SZ_HID)               // metaP [b][h][p][24]
#define SZ_MP     ((size_t)B_*NH_*P_*24)
#define OFF_MA    (OFF_MP + SZ_MP)                 // metaA [b][h][p][12]
#define SZ_MA     ((size_t)B_*NH_*P_*12)
#define OFF_ST    (OFF_MA + SZ_MA)                 // GN stats [br][b][g][2]
#define SZ_ST     ((size_t)128)
#define OFF_BE    (OFF_ST + SZ_ST)                 // vp effective bias [l][128]
#define SZ_BE     ((size_t)(NL_*C_))

typedef short bf16x8 __attribute__((ext_vector_type(8)));
typedef float f32x4  __attribute__((ext_vector_type(4)));
#define MFMA16(a,b,c) __builtin_amdgcn_mfma_f32_16x16x32_bf16(a,b,c,0,0,0)

// split fp32 -> bf16 hi + bf16 lo (truncation; rem is exact, total rel err ~2^-16)
__device__ __forceinline__ void cvt8(const float* __restrict__ x, bf16x8& hi, bf16x8& lo) {
#pragma unroll
    for (int j = 0; j < 8; ++j) {
        unsigned ub = __float_as_uint(x[j]);
        hi[j] = (short)(ub >> 16);
        float rem = x[j] - __uint_as_float(ub & 0xffff0000u);
        lo[j] = (short)(__float_as_uint(rem) >> 16);
    }
}

// ---------------------------------------------------------------------------
// prep: zero GN stats; fold level_embed into vp bias
__global__ void k_prep(const float* __restrict__ vp_w, const float* __restrict__ vp_b,
                       const float* __restrict__ le, float* __restrict__ bias_eff,
                       float* __restrict__ stats)
{
    const int t = threadIdx.x;            // 384 threads
    if (t < 128) stats[t] = 0.f;
    const int l = t >> 7;
    const int o = t & 127;
    float d = vp_b[o];
    for (int k = 0; k < 128; ++k) d = fmaf(vp_w[o*128 + k], le[l*128 + k], d);
    bias_eff[l*128 + o] = d;
}

// ---------------------------------------------------------------------------
// MFMA value projection: v[b][l][p][c], pixel-major output
__global__ __launch_bounds__(256) void k_vproj(
    const float* __restrict__ vals, const float* __restrict__ vp_w,
    const float* __restrict__ bias_eff, float* __restrict__ v_ws)
{
    const int tid = threadIdx.x;
    const int wv = tid >> 6, l = tid & 63;
    const int lr = l & 15, lg = l >> 4;
    const int bl = blockIdx.y, lvl = bl % NL_;
    const int px0 = blockIdx.x * 64;
    const float* __restrict__ X = vals + (size_t)bl*C_*P_;

    // A fragments: W rows oc = wv*32 + rt*16 + lr ; k = t*32 + lg*8 + j (contiguous)
    bf16x8 Ahi[2][4], Alo[2][4];
#pragma unroll
    for (int rt = 0; rt < 2; ++rt)
#pragma unroll
        for (int t = 0; t < 4; ++t) {
            const float* wr = vp_w + (size_t)(wv*32 + rt*16 + lr)*128 + t*32 + lg*8;
            float x8[8];
            float4 a = *(const float4*)wr, b = *(const float4*)(wr + 4);
            x8[0]=a.x; x8[1]=a.y; x8[2]=a.z; x8[3]=a.w;
            x8[4]=b.x; x8[5]=b.y; x8[6]=b.z; x8[7]=b.w;
            cvt8(x8, Ahi[rt][t], Alo[rt][t]);
        }

    f32x4 acc[2][4];
#pragma unroll
    for (int rt = 0; rt < 2; ++rt)
#pragma unroll
        for (int c = 0; c < 4; ++c)
#pragma unroll
            for (int r = 0; r < 4; ++r) acc[rt][c][r] = 0.f;

#pragma unroll
    for (int c = 0; c < 4; ++c) {
        const int px = px0 + c*16 + lr;
#pragma unroll
        for (int t = 0; t < 4; ++t) {
            const float* xp = X + (size_t)(t*32 + lg*8)*P_ + px;
            float x8[8];
#pragma unroll
            for (int j = 0; j < 8; ++j) x8[j] = xp[(size_t)j*P_];
            bf16x8 bhi, blo; cvt8(x8, bhi, blo);
#pragma unroll
            for (int rt = 0; rt < 2; ++rt) {
                acc[rt][c] = MFMA16(Ahi[rt][t], bhi, acc[rt][c]);
                acc[rt][c] = MFMA16(Alo[rt][t], bhi, acc[rt][c]);
                acc[rt][c] = MFMA16(Ahi[rt][t], blo, acc[rt][c]);
            }
        }
    }

    const float* be = bias_eff + lvl*128;
#pragma unroll
    for (int c = 0; c < 4; ++c) {
        const int px = px0 + c*16 + lr;
        float* op = v_ws + ((size_t)bl*P_ + px)*C_ + wv*32 + lg*4;
#pragma unroll
        for (int rt = 0; rt < 2; ++rt) {
            const int oc = wv*32 + rt*16 + lg*4;
            float4 r;
            r.x = acc[rt][c][0] + be[oc+0];
            r.y = acc[rt][c][1] + be[oc+1];
            r.z = acc[rt][c][2] + be[oc+2];
            r.w = acc[rt][c][3] + be[oc+3];
            *(float4*)(op + rt*16) = r;
        }
    }
}

// ---------------------------------------------------------------------------
// MFMA conv1 (both branches via waves): hid = W1*query + b1 (channel-major) + GN stats
__global__ __launch_bounds__(256) void k_conv1(
    const float* __restrict__ q,
    const float* __restrict__ w_so, const float* __restrict__ b_so,
    const float* __restrict__ w_aw, const float* __restrict__ b_aw,
    float* __restrict__ hid, float* __restrict__ stats)
{
    const int tid = threadIdx.x;
    const int wv = tid >> 6, l = tid & 63;
    const int lr = l & 15, lg = l >> 4;
    const int b = blockIdx.y;
    const int br = wv >> 1, oc0 = (wv & 1) * 32;
    const float* __restrict__ W  = br ? w_aw : w_so;
    const float* __restrict__ bi = br ? b_aw : b_so;
    const float* __restrict__ X  = q + (size_t)b*C_*P_;
    const int px0 = blockIdx.x * 64;

    bf16x8 Ahi[2][4], Alo[2][4];
#pragma unroll
    for (int rt = 0; rt < 2; ++rt)
#pragma unroll
        for (int t = 0; t < 4; ++t) {
            const float* wr = W + (size_t)(oc0 + rt*16 + lr)*128 + t*32 + lg*8;
            float x8[8];
            float4 a = *(const float4*)wr, bb = *(const float4*)(wr + 4);
            x8[0]=a.x; x8[1]=a.y; x8[2]=a.z; x8[3]=a.w;
            x8[4]=bb.x; x8[5]=bb.y; x8[6]=bb.z; x8[7]=bb.w;
            cvt8(x8, Ahi[rt][t], Alo[rt][t]);
        }

    f32x4 acc[2][4];
#pragma unroll
    for (int rt = 0; rt < 2; ++rt)
#pragma unroll
        for (int c = 0; c < 4; ++c)
#pragma unroll
            for (int r = 0; r < 4; ++r) acc[rt][c][r] = 0.f;

#pragma unroll
    for (int c = 0; c < 4; ++c) {
        const int px = px0 + c*16 + lr;
#pragma unroll
        for (int t = 0; t < 4; ++t) {
            const float* xp = X + (size_t)(t*32 + lg*8)*P_ + px;
            float x8[8];
#pragma unroll
            for (int j = 0; j < 8; ++j) x8[j] = xp[(size_t)j*P_];
            bf16x8 bhi, blo; cvt8(x8, bhi, blo);
#pragma unroll
            for (int rt = 0; rt < 2; ++rt) {
                acc[rt][c] = MFMA16(Ahi[rt][t], bhi, acc[rt][c]);
                acc[rt][c] = MFMA16(Alo[rt][t], bhi, acc[rt][c]);
                acc[rt][c] = MFMA16(Ahi[rt][t], blo, acc[rt][c]);
            }
        }
    }

    float* hb = hid + ((size_t)(br*B_ + b)*C2_)*P_;
#pragma unroll
    for (int rt = 0; rt < 2; ++rt) {
        float s = 0.f, ss = 0.f;
#pragma unroll
        for (int c = 0; c < 4; ++c) {
            const int px = px0 + c*16 + lr;
#pragma unroll
            for (int r = 0; r < 4; ++r) {
                const int oc = oc0 + rt*16 + lg*4 + r;
                float v = acc[rt][c][r] + bi[oc];
                hb[(size_t)oc*P_ + px] = v;
                s += v; ss += v*v;
            }
        }
#pragma unroll
        for (int off = 16; off > 0; off >>= 1) {
            s  += __shfl_xor(s,  off, 64);
            ss += __shfl_xor(ss, off, 64);
        }
        if ((l & 31) == 0) {
            const int g = (oc0 + rt*16 + (l >> 4)*4) >> 3;
            atomicAdd(&stats[((br*B_ + b)*8 + g)*2 + 0], s);
            atomicAdd(&stats[((br*B_ + b)*8 + g)*2 + 1], ss);
        }
    }
}

// ---------------------------------------------------------------------------
// conv2 + meta (unchanged fp32)
__global__ __launch_bounds__(256) void k_conv2(
    const float* __restrict__ hid, const float* __restrict__ stats,
    const float* __restrict__ so_g, const float* __restrict__ so_be,
    const float* __restrict__ aw_g, const float* __restrict__ aw_be,
    const float* __restrict__ so_w2, const float* __restrict__ so_b2,
    const float* __restrict__ aw_w2, const float* __restrict__ aw_b2,
    float* __restrict__ metaP, float* __restrict__ metaA)
{
    __shared__ float sc[2][64], sh[2][64];
    const int tid = threadIdx.x;
    const int b = blockIdx.y;
    if (tid < 128) {
        const int br = tid >> 6, c = tid & 63, g = c >> 3;
        const float ninv = 1.f/(8.f*(float)P_);
        float s  = stats[((br*B_ + b)*8 + g)*2 + 0];
        float ss = stats[((br*B_ + b)*8 + g)*2 + 1];
        float mu  = s*ninv;
        float var = ss*ninv - mu*mu;
        float rs  = rsqrtf(var + 1e-5f);
        float ga = br ? aw_g[c]  : so_g[c];
        float be = br ? aw_be[c] : so_be[c];
        sc[br][c] = ga*rs;
        sh[br][c] = be - mu*ga*rs;
    }
    __syncthreads();

    const int p = blockIdx.x*256 + tid;
    const int x = p & (W_-1), y = p >> 7;
    const float refx = (float)x * (1.f/(float)(W_-1));
    const float refy = (float)y * (1.f/(float)(H_-1));

    float h[64];
    {
        const float* hs = hid + ((size_t)(0*B_ + b)*C2_)*P_ + p;
#pragma unroll
        for (int k = 0; k < 64; ++k)
            h[k] = fmaxf(fmaf(hs[(size_t)k*P_], sc[0][k], sh[0][k]), 0.f);
    }
    for (int hh = 0; hh < NH_; ++hh) {
        float2* mp = (float2*)(metaP + ((size_t)(b*NH_ + hh)*P_ + p)*24);
        for (int s = 0; s < 12; ++s) {
            const int oc = (hh*12 + s)*2;
            const float* w0 = so_w2 + (size_t)oc*64;
            const float* w1 = w0 + 64;
            float a0=0.f,a1=0.f,c0=0.f,c1=0.f;
#pragma unroll
            for (int k = 0; k < 64; k += 2) {
                a0 = fmaf(w0[k],   h[k],   a0);
                a1 = fmaf(w0[k+1], h[k+1], a1);
                c0 = fmaf(w1[k],   h[k],   c0);
                c1 = fmaf(w1[k+1], h[k+1], c1);
            }
            float ox = a0+a1 + so_b2[oc];
            float oy = c0+c1 + so_b2[oc+1];
            float lx = fminf(fmaxf(refx + ox*(1.f/(float)W_), 0.f), 1.f);
            float ly = fminf(fmaxf(refy + oy*(1.f/(float)H_), 0.f), 1.f);
            mp[s] = make_float2(lx*(float)W_ - 0.5f, ly*(float)H_ - 0.5f);
        }
    }
    {
        const float* ha = hid + ((size_t)(1*B_ + b)*C2_)*P_ + p;
#pragma unroll
        for (int k = 0; k < 64; ++k)
            h[k] = fmaxf(fmaf(ha[(size_t)k*P_], sc[1][k], sh[1][k]), 0.f);
    }
    for (int hh = 0; hh < NH_; ++hh) {
        float a[12];
#pragma unroll
        for (int s = 0; s < 12; ++s) {
            const int oc = hh*12 + s;
            const float* wr = aw_w2 + (size_t)oc*64;
            float d0=0.f,d1=0.f;
#pragma unroll
            for (int k = 0; k < 64; k += 2) {
                d0 = fmaf(wr[k],   h[k],   d0);
                d1 = fmaf(wr[k+1], h[k+1], d1);
            }
            a[s] = d0+d1 + aw_b2[oc];
        }
        float m = a[0];
#pragma unroll
        for (int s = 1; s < 12; ++s) m = fmaxf(m, a[s]);
        float sum = 0.f;
#pragma unroll
        for (int s = 0; s < 12; ++s) { a[s] = __expf(a[s]-m); sum += a[s]; }
        const float inv = 1.f/sum;
        float* ma = metaA + ((size_t)(b*NH_ + hh)*P_ + p)*12;
#pragma unroll
        for (int s = 0; s < 12; ++s) ma[s] = a[s]*inv;
    }
}

// ---------------------------------------------------------------------------
// bilinear sampling + attention-weighted sum (unchanged)
__global__ __launch_bounds__(256) void k_sample(
    const float* __restrict__ v_ws, const float* __restrict__ metaP,
    const float* __restrict__ metaA, float* __restrict__ out_pre)
{
    const int tid = threadIdx.x;
    const int u  = tid >> 2;
    const int c4 = tid & 3;
    const int p  = blockIdx.x*64 + u;
    const int hh = blockIdx.y, b = blockIdx.z;

    const size_t mbase = (size_t)(b*NH_ + hh)*P_ + p;
    const float4* mp4 = (const float4*)(metaP + mbase*24);
    const float4* ma4 = (const float4*)(metaA + mbase*12);

    float pxv[12], pyv[12], av[12];
#pragma unroll
    for (int i = 0; i < 6; ++i) {
        float4 m = mp4[i];
        pxv[i*2]   = m.x; pyv[i*2]   = m.y;
        pxv[i*2+1] = m.z; pyv[i*2+1] = m.w;
    }
#pragma unroll
    for (int i = 0; i < 3; ++i) {
        float4 m = ma4[i];
        av[i*4]=m.x; av[i*4+1]=m.y; av[i*4+2]=m.z; av[i*4+3]=m.w;
    }

    float ax=0.f, ay=0.f, az=0.f, aw=0.f;
#pragma unroll
    for (int l = 0; l < NL_; ++l) {
        const float4* vb = (const float4*)(v_ws + ((size_t)(b*NL_ + l)*P_)*C_ + hh*HD_ + c4*4);
#pragma unroll
        for (int pt = 0; pt < NP_; ++pt) {
            const int s = l*4 + pt;
            float px = fminf(fmaxf(pxv[s], 0.f), (float)(W_-1));
            float py = fminf(fmaxf(pyv[s], 0.f), (float)(H_-1));
            float x0f = floorf(px), y0f = floorf(py);
            float wx = px - x0f, wy = py - y0f;
            int x0 = (int)x0f, y0 = (int)y0f;
            int x1 = min(x0+1, W_-1), y1 = min(y0+1, H_-1);
            const float4* r0 = vb + (size_t)(y0*W_)*32;
            const float4* r1 = vb + (size_t)(y1*W_)*32;
            float4 v00 = r0[(size_t)x0*32], v01 = r0[(size_t)x1*32];
            float4 v10 = r1[(size_t)x0*32], v11 = r1[(size_t)x1*32];
            float tx, bx2, val;
            float a = av[s];
            tx = v00.x + (v01.x - v00.x)*wx; bx2 = v10.x + (v11.x - v10.x)*wx;
            val = tx + (bx2 - tx)*wy;  ax = fmaf(a, val, ax);
            tx = v00.y + (v01.y - v00.y)*wx; bx2 = v10.y + (v11.y - v10.y)*wx;
            val = tx + (bx2 - tx)*wy;  ay = fmaf(a, val, ay);
            tx = v00.z + (v01.z - v00.z)*wx; bx2 = v10.z + (v11.z - v10.z)*wx;
            val = tx + (bx2 - tx)*wy;  az = fmaf(a, val, az);
            tx = v00.w + (v01.w - v00.w)*wx; bx2 = v10.w + (v11.w - v10.w)*wx;
            val = tx + (bx2 - tx)*wy;  aw = fmaf(a, val, aw);
        }
    }
    float4* op = (float4*)(out_pre + ((size_t)b*P_ + p)*C_ + hh*HD_ + c4*4);
    *op = make_float4(ax, ay, az, aw);
}

// ---------------------------------------------------------------------------
// MFMA final conv: out[b][oc][p] = op_w . out_pre[b][p][:] + op_b
__global__ __launch_bounds__(256) void k_convout(
    const float* __restrict__ inp, const float* __restrict__ op_w,
    const float* __restrict__ op_b, float* __restrict__ out)
{
    const int tid = threadIdx.x;
    const int wv = tid >> 6, l = tid & 63;
    const int lr = l & 15, lg = l >> 4;
    const int b = blockIdx.y;
    const int px0 = blockIdx.x * 64;

    bf16x8 Ahi[2][4], Alo[2][4];
#pragma unroll
    for (int rt = 0; rt < 2; ++rt)
#pragma unroll
        for (int t = 0; t < 4; ++t) {
            const float* wr = op_w + (size_t)(wv*32 + rt*16 + lr)*128 + t*32 + lg*8;
            float x8[8];
            float4 a = *(const float4*)wr, bb = *(const float4*)(wr + 4);
            x8[0]=a.x; x8[1]=a.y; x8[2]=a.z; x8[3]=a.w;
            x8[4]=bb.x; x8[5]=bb.y; x8[6]=bb.z; x8[7]=bb.w;
            cvt8(x8, Ahi[rt][t], Alo[rt][t]);
        }

    f32x4 acc[2][4];
#pragma unroll
    for (int rt = 0; rt < 2; ++rt)
#pragma unroll
        for (int c = 0; c < 4; ++c)
#pragma unroll
            for (int r = 0; r < 4; ++r) acc[rt][c][r] = 0.f;

#pragma unroll
    for (int c = 0; c < 4; ++c) {
        const int px = px0 + c*16 + lr;
        const float* xb = inp + ((size_t)b*P_ + px)*C_;
#pragma unroll
        for (int t = 0; t < 4; ++t) {
            const float* xp = xb + t*32 + lg*8;
            float x8[8];
            float4 a = *(const float4*)xp, bb = *(const float4*)(xp + 4);
            x8[0]=a.x; x8[1]=a.y; x8[2]=a.z; x8[3]=a.w;
            x8[4]=bb.x; x8[5]=bb.y; x8[6]=bb.z; x8[7]=bb.w;
            bf16x8 bhi, blo; cvt8(x8, bhi, blo);
#pragma unroll
            for (int rt = 0; rt < 2; ++rt) {
                acc[rt][c] = MFMA16(Ahi[rt][t], bhi, acc[rt][c]);
                acc[rt][c] = MFMA16(Alo[rt][t], bhi, acc[rt][c]);
                acc[rt][c] = MFMA16(Ahi[rt][t], blo, acc[rt][c]);
            }
        }
    }

    float* ob = out + (size_t)b*C_*P_;
#pragma unroll
    for (int rt = 0; rt < 2; ++rt)
#pragma unroll
        for (int c = 0; c < 4; ++c) {
            const int px = px0 + c*16 + lr;
#pragma unroll
            for (int r = 0; r < 4; ++r) {
                const int oc = wv*32 + rt*16 + lg*4 + r;
                ob[(size_t)oc*P_ + px] = acc[rt][c][r] + op_b[oc];
            }
        }
}

// ---------------------------------------------------------------------------
extern "C" void kernel_launch(void* const* d_in, const int* in_sizes, int n_in,
                              void* d_out, int out_size, void* d_ws, size_t ws_size,
                              hipStream_t stream)
{
    const float* query = (const float*)d_in[0];
    // d_in[1] = keys : UNUSED by reference
    const float* values = (const float*)d_in[2];
    const float* so_w1 = (const float*)d_in[3];
    const float* so_b1 = (const float*)d_in[4];
    const float* so_g  = (const float*)d_in[5];
    const float* so_be = (const float*)d_in[6];
    const float* so_w2 = (const float*)d_in[7];
    const float* so_b2 = (const float*)d_in[8];
    const float* aw_w1 = (const float*)d_in[9];
    const float* aw_b1 = (const float*)d_in[10];
    const float* aw_g  = (const float*)d_in[11];
    const float* aw_be = (const float*)d_in[12];
    const float* aw_w2 = (const float*)d_in[13];
    const float* aw_b2 = (const float*)d_in[14];
    const float* vp_w  = (const float*)d_in[15];
    const float* vp_b  = (const float*)d_in[16];
    const float* op_w  = (const float*)d_in[17];
    const float* op_b  = (const float*)d_in[18];
    const float* le    = (const float*)d_in[19];

    float* ws      = (float*)d_ws;
    float* v_ws    = ws + OFF_V;
    float* hid     = ws + OFF_HID;
    float* metaP   = ws + OFF_MP;
    float* metaA   = ws + OFF_MA;
    float* stats   = ws + OFF_ST;
    float* be      = ws + OFF_BE;
    float* out_pre = hid;                 // hid dead after k_conv2 -> reuse
    float* out     = (float*)d_out;

    k_prep<<<dim3(1), dim3(384), 0, stream>>>(vp_w, vp_b, le, be, stats);
    k_vproj<<<dim3(P_/64, B_*NL_), dim3(256), 0, stream>>>(values, vp_w, be, v_ws);
    k_conv1<<<dim3(P_/64, B_), dim3(256), 0, stream>>>(query, so_w1, so_b1, aw_w1, aw_b1, hid, stats);
    k_conv2<<<dim3(P_/256, B_), dim3(256), 0, stream>>>(hid, stats, so_g, so_be, aw_g, aw_be,
                                                        so_w2, so_b2, aw_w2, aw_b2, metaP, metaA);
    k_sample<<<dim3(P_/64, NH_, B_), dim3(256), 0, stream>>>(v_ws, metaP, metaA, out_pre);
    k_convout<<<dim3(P_/64, B_), dim3(256), 0, stream>>>(out_pre, op_w, op_b, out);
}

// Round 3
// 363.803 us; speedup vs baseline: 4.3126x; 1.6937x over previous
//
#include <hip/hip_runtime.h>
#include <cstdint>
#include <cstddef>

#define B_ 4
#define C_ 128
#define H_ 128
#define W_ 128
#define P_ (H_*W_)       // 16384
#define NH_ 8
#define NL_ 3
#define NP_ 4
#define HD_ 16
#define C2_ 64

// ---- workspace layout (float elements) ----
#define SZ_V      ((size_t)B_*NL_*P_*C_)          // v projected, pixel-major [b][l][p][c]
#define OFF_V     ((size_t)0)
#define OFF_HID   (OFF_V + SZ_V)                   // hid [br][b][c][p], later reused as out_pre [b][p][c]
#define SZ_HID    ((size_t)2*B_*C2_*P_)
#define OFF_MP    (OFF_HID + SZ_HID)               // metaP [b][h][p][24]
#define SZ_MP     ((size_t)B_*NH_*P_*24)
#define OFF_MA    (OFF_MP + SZ_MP)                 // metaA [b][h][p][12]
#define SZ_MA     ((size_t)B_*NH_*P_*12)
#define OFF_ST    (OFF_MA + SZ_MA)                 // GN stats [br][b][g][2]
#define SZ_ST     ((size_t)128)
#define OFF_BE    (OFF_ST + SZ_ST)                 // vp effective bias [l][128]
#define SZ_BE     ((size_t)(NL_*C_))

typedef short bf16x8 __attribute__((ext_vector_type(8)));
typedef float f32x4  __attribute__((ext_vector_type(4)));
#define MFMA16(a,b,c) __builtin_amdgcn_mfma_f32_16x16x32_bf16(a,b,c,0,0,0)

// split fp32 -> bf16 hi + bf16 lo (truncation; rem is exact, total rel err ~2^-16)
__device__ __forceinline__ void cvt8(const float* __restrict__ x, bf16x8& hi, bf16x8& lo) {
#pragma unroll
    for (int j = 0; j < 8; ++j) {
        unsigned ub = __float_as_uint(x[j]);
        hi[j] = (short)(ub >> 16);
        float rem = x[j] - __uint_as_float(ub & 0xffff0000u);
        lo[j] = (short)(__float_as_uint(rem) >> 16);
    }
}

// ---------------------------------------------------------------------------
// prep: zero GN stats; fold level_embed into vp bias
__global__ void k_prep(const float* __restrict__ vp_w, const float* __restrict__ vp_b,
                       const float* __restrict__ le, float* __restrict__ bias_eff,
                       float* __restrict__ stats)
{
    const int t = threadIdx.x;            // 384 threads
    if (t < 128) stats[t] = 0.f;
    const int l = t >> 7;
    const int o = t & 127;
    float d = vp_b[o];
    for (int k = 0; k < 128; ++k) d = fmaf(vp_w[o*128 + k], le[l*128 + k], d);
    bias_eff[l*128 + o] = d;
}

// ---------------------------------------------------------------------------
// MFMA value projection: v[b][l][p][c], pixel-major output
__global__ __launch_bounds__(256) void k_vproj(
    const float* __restrict__ vals, const float* __restrict__ vp_w,
    const float* __restrict__ bias_eff, float* __restrict__ v_ws)
{
    const int tid = threadIdx.x;
    const int wv = tid >> 6, l = tid & 63;
    const int lr = l & 15, lg = l >> 4;
    const int bl = blockIdx.y, lvl = bl % NL_;
    const int px0 = blockIdx.x * 64;
    const float* __restrict__ X = vals + (size_t)bl*C_*P_;

    bf16x8 Ahi[2][4], Alo[2][4];
#pragma unroll
    for (int rt = 0; rt < 2; ++rt)
#pragma unroll
        for (int t = 0; t < 4; ++t) {
            const float* wr = vp_w + (size_t)(wv*32 + rt*16 + lr)*128 + t*32 + lg*8;
            float x8[8];
            float4 a = *(const float4*)wr, b = *(const float4*)(wr + 4);
            x8[0]=a.x; x8[1]=a.y; x8[2]=a.z; x8[3]=a.w;
            x8[4]=b.x; x8[5]=b.y; x8[6]=b.z; x8[7]=b.w;
            cvt8(x8, Ahi[rt][t], Alo[rt][t]);
        }

    f32x4 acc[2][4];
#pragma unroll
    for (int rt = 0; rt < 2; ++rt)
#pragma unroll
        for (int c = 0; c < 4; ++c)
#pragma unroll
            for (int r = 0; r < 4; ++r) acc[rt][c][r] = 0.f;

#pragma unroll
    for (int c = 0; c < 4; ++c) {
        const int px = px0 + c*16 + lr;
#pragma unroll
        for (int t = 0; t < 4; ++t) {
            const float* xp = X + (size_t)(t*32 + lg*8)*P_ + px;
            float x8[8];
#pragma unroll
            for (int j = 0; j < 8; ++j) x8[j] = xp[(size_t)j*P_];
            bf16x8 bhi, blo; cvt8(x8, bhi, blo);
#pragma unroll
            for (int rt = 0; rt < 2; ++rt) {
                acc[rt][c] = MFMA16(Ahi[rt][t], bhi, acc[rt][c]);
                acc[rt][c] = MFMA16(Alo[rt][t], bhi, acc[rt][c]);
                acc[rt][c] = MFMA16(Ahi[rt][t], blo, acc[rt][c]);
            }
        }
    }

    const float* be = bias_eff + lvl*128;
#pragma unroll
    for (int c = 0; c < 4; ++c) {
        const int px = px0 + c*16 + lr;
        float* op = v_ws + ((size_t)bl*P_ + px)*C_ + wv*32 + lg*4;
#pragma unroll
        for (int rt = 0; rt < 2; ++rt) {
            const int oc = wv*32 + rt*16 + lg*4;
            float4 r;
            r.x = acc[rt][c][0] + be[oc+0];
            r.y = acc[rt][c][1] + be[oc+1];
            r.z = acc[rt][c][2] + be[oc+2];
            r.w = acc[rt][c][3] + be[oc+3];
            *(float4*)(op + rt*16) = r;
        }
    }
}

// ---------------------------------------------------------------------------
// MFMA conv1 (both branches via waves): hid = W1*query + b1 (channel-major) + GN stats
__global__ __launch_bounds__(256) void k_conv1(
    const float* __restrict__ q,
    const float* __restrict__ w_so, const float* __restrict__ b_so,
    const float* __restrict__ w_aw, const float* __restrict__ b_aw,
    float* __restrict__ hid, float* __restrict__ stats)
{
    const int tid = threadIdx.x;
    const int wv = tid >> 6, l = tid & 63;
    const int lr = l & 15, lg = l >> 4;
    const int b = blockIdx.y;
    const int br = wv >> 1, oc0 = (wv & 1) * 32;
    const float* __restrict__ W  = br ? w_aw : w_so;
    const float* __restrict__ bi = br ? b_aw : b_so;
    const float* __restrict__ X  = q + (size_t)b*C_*P_;
    const int px0 = blockIdx.x * 64;

    bf16x8 Ahi[2][4], Alo[2][4];
#pragma unroll
    for (int rt = 0; rt < 2; ++rt)
#pragma unroll
        for (int t = 0; t < 4; ++t) {
            const float* wr = W + (size_t)(oc0 + rt*16 + lr)*128 + t*32 + lg*8;
            float x8[8];
            float4 a = *(const float4*)wr, bb = *(const float4*)(wr + 4);
            x8[0]=a.x; x8[1]=a.y; x8[2]=a.z; x8[3]=a.w;
            x8[4]=bb.x; x8[5]=bb.y; x8[6]=bb.z; x8[7]=bb.w;
            cvt8(x8, Ahi[rt][t], Alo[rt][t]);
        }

    f32x4 acc[2][4];
#pragma unroll
    for (int rt = 0; rt < 2; ++rt)
#pragma unroll
        for (int c = 0; c < 4; ++c)
#pragma unroll
            for (int r = 0; r < 4; ++r) acc[rt][c][r] = 0.f;

#pragma unroll
    for (int c = 0; c < 4; ++c) {
        const int px = px0 + c*16 + lr;
#pragma unroll
        for (int t = 0; t < 4; ++t) {
            const float* xp = X + (size_t)(t*32 + lg*8)*P_ + px;
            float x8[8];
#pragma unroll
            for (int j = 0; j < 8; ++j) x8[j] = xp[(size_t)j*P_];
            bf16x8 bhi, blo; cvt8(x8, bhi, blo);
#pragma unroll
            for (int rt = 0; rt < 2; ++rt) {
                acc[rt][c] = MFMA16(Ahi[rt][t], bhi, acc[rt][c]);
                acc[rt][c] = MFMA16(Alo[rt][t], bhi, acc[rt][c]);
                acc[rt][c] = MFMA16(Ahi[rt][t], blo, acc[rt][c]);
            }
        }
    }

    float* hb = hid + ((size_t)(br*B_ + b)*C2_)*P_;
#pragma unroll
    for (int rt = 0; rt < 2; ++rt) {
        float s = 0.f, ss = 0.f;
#pragma unroll
        for (int c = 0; c < 4; ++c) {
            const int px = px0 + c*16 + lr;
#pragma unroll
            for (int r = 0; r < 4; ++r) {
                const int oc = oc0 + rt*16 + lg*4 + r;
                float v = acc[rt][c][r] + bi[oc];
                hb[(size_t)oc*P_ + px] = v;
                s += v; ss += v*v;
            }
        }
#pragma unroll
        for (int off = 16; off > 0; off >>= 1) {
            s  += __shfl_xor(s,  off, 64);
            ss += __shfl_xor(ss, off, 64);
        }
        if ((l & 31) == 0) {
            const int g = (oc0 + rt*16 + (l >> 4)*4) >> 3;
            atomicAdd(&stats[((br*B_ + b)*8 + g)*2 + 0], s);
            atomicAdd(&stats[((br*B_ + b)*8 + g)*2 + 1], ss);
        }
    }
}

// ---------------------------------------------------------------------------
// MFMA conv2 + meta: GN+ReLU on B-operand, 2-phase LDS, fused post-processing.
// Block = 256 threads (4 waves x 16 pixels), grid (P/64, B) = 1024 blocks.
__global__ __launch_bounds__(256) void k_conv2(
    const float* __restrict__ hid, const float* __restrict__ stats,
    const float* __restrict__ so_g, const float* __restrict__ so_be,
    const float* __restrict__ aw_g, const float* __restrict__ aw_be,
    const float* __restrict__ so_w2, const float* __restrict__ so_b2,
    const float* __restrict__ aw_w2, const float* __restrict__ aw_b2,
    float* __restrict__ metaP, float* __restrict__ metaA)
{
    __shared__ float sc[2][64], sh[2][64];
    __shared__ float S[192*66];           // padded cols: <=2-way bank aliasing
    const int tid = threadIdx.x;
    const int wv = tid >> 6, l = tid & 63;
    const int lr = l & 15, lg = l >> 4;
    const int b = blockIdx.y;
    const int px0 = blockIdx.x * 64;

    if (tid < 128) {
        const int br = tid >> 6, c = tid & 63, g = c >> 3;
        const float ninv = 1.f/(8.f*(float)P_);
        float s  = stats[((br*B_ + b)*8 + g)*2 + 0];
        float ss = stats[((br*B_ + b)*8 + g)*2 + 1];
        float mu  = s*ninv;
        float var = ss*ninv - mu*mu;
        float rs  = rsqrtf(var + 1e-5f);
        float ga = br ? aw_g[c]  : so_g[c];
        float be = br ? aw_be[c] : so_be[c];
        sc[br][c] = ga*rs;
        sh[br][c] = be - mu*ga*rs;
    }
    __syncthreads();

    const int pxw = px0 + wv*16 + lr;     // this lane's pixel (MFMA B / D col)

    // ---- phase A: offset branch (192 ch) ----
    bf16x8 Bhi[2], Blo[2];
    {
        const float* hs = hid + ((size_t)(0*B_ + b)*C2_)*P_ + pxw;
#pragma unroll
        for (int t = 0; t < 2; ++t) {
            float x8[8];
#pragma unroll
            for (int j = 0; j < 8; ++j) {
                const int k = t*32 + lg*8 + j;
                x8[j] = fmaxf(fmaf(hs[(size_t)k*P_], sc[0][k], sh[0][k]), 0.f);
            }
            cvt8(x8, Bhi[t], Blo[t]);
        }
    }
#pragma unroll
    for (int tile = 0; tile < 12; ++tile) {
        f32x4 acc; acc[0]=0.f; acc[1]=0.f; acc[2]=0.f; acc[3]=0.f;
#pragma unroll
        for (int t = 0; t < 2; ++t) {
            const float* wr = so_w2 + (size_t)(tile*16 + lr)*64 + t*32 + lg*8;
            float x8[8];
            float4 a = *(const float4*)wr, bb = *(const float4*)(wr + 4);
            x8[0]=a.x; x8[1]=a.y; x8[2]=a.z; x8[3]=a.w;
            x8[4]=bb.x; x8[5]=bb.y; x8[6]=bb.z; x8[7]=bb.w;
            bf16x8 ahi, alo; cvt8(x8, ahi, alo);
            acc = MFMA16(ahi, Bhi[t], acc);
            acc = MFMA16(alo, Bhi[t], acc);
            acc = MFMA16(ahi, Blo[t], acc);
        }
#pragma unroll
        for (int r = 0; r < 4; ++r) {
            const int ch = tile*16 + lg*4 + r;
            S[ch*66 + wv*16 + lr] = acc[r] + so_b2[ch];
        }
    }
    __syncthreads();

    // ---- post A: offsets -> clipped pixel coords ----
    {
        const int pl = tid & 63, sub = tid >> 6;
        const int p = px0 + pl;
        const int x = p & (W_-1), y = p >> 7;
        const float refx = (float)x * (1.f/(float)(W_-1));
        const float refy = (float)y * (1.f/(float)(H_-1));
#pragma unroll
        for (int hi = 0; hi < 2; ++hi) {
            const int hh = sub*2 + hi;
            float2 buf[12];
#pragma unroll
            for (int s = 0; s < 12; ++s) {
                float ox = S[(hh*24 + 2*s    )*66 + pl];
                float oy = S[(hh*24 + 2*s + 1)*66 + pl];
                float lx = fminf(fmaxf(refx + ox*(1.f/(float)W_), 0.f), 1.f);
                float ly = fminf(fmaxf(refy + oy*(1.f/(float)H_), 0.f), 1.f);
                buf[s] = make_float2(lx*(float)W_ - 0.5f, ly*(float)H_ - 0.5f);
            }
            float4* mp = (float4*)(metaP + ((size_t)(b*NH_ + hh)*P_ + p)*24);
#pragma unroll
            for (int i = 0; i < 6; ++i)
                mp[i] = make_float4(buf[2*i].x, buf[2*i].y, buf[2*i+1].x, buf[2*i+1].y);
        }
    }
    __syncthreads();

    // ---- phase B: attn branch (96 ch) ----
    {
        const float* hs = hid + ((size_t)(1*B_ + b)*C2_)*P_ + pxw;
#pragma unroll
        for (int t = 0; t < 2; ++t) {
            float x8[8];
#pragma unroll
            for (int j = 0; j < 8; ++j) {
                const int k = t*32 + lg*8 + j;
                x8[j] = fmaxf(fmaf(hs[(size_t)k*P_], sc[1][k], sh[1][k]), 0.f);
            }
            cvt8(x8, Bhi[t], Blo[t]);
        }
    }
#pragma unroll
    for (int tile = 0; tile < 6; ++tile) {
        f32x4 acc; acc[0]=0.f; acc[1]=0.f; acc[2]=0.f; acc[3]=0.f;
#pragma unroll
        for (int t = 0; t < 2; ++t) {
            const float* wr = aw_w2 + (size_t)(tile*16 + lr)*64 + t*32 + lg*8;
            float x8[8];
            float4 a = *(const float4*)wr, bb = *(const float4*)(wr + 4);
            x8[0]=a.x; x8[1]=a.y; x8[2]=a.z; x8[3]=a.w;
            x8[4]=bb.x; x8[5]=bb.y; x8[6]=bb.z; x8[7]=bb.w;
            bf16x8 ahi, alo; cvt8(x8, ahi, alo);
            acc = MFMA16(ahi, Bhi[t], acc);
            acc = MFMA16(alo, Bhi[t], acc);
            acc = MFMA16(ahi, Blo[t], acc);
        }
#pragma unroll
        for (int r = 0; r < 4; ++r) {
            const int ch = tile*16 + lg*4 + r;
            S[ch*66 + wv*16 + lr] = acc[r] + aw_b2[ch];
        }
    }
    __syncthreads();

    // ---- post B: per-head softmax over 12 ----
    {
        const int pl = tid & 63, sub = tid >> 6;
        const int p = px0 + pl;
#pragma unroll
        for (int hi = 0; hi < 2; ++hi) {
            const int hh = sub*2 + hi;
            float a[12];
#pragma unroll
            for (int s = 0; s < 12; ++s) a[s] = S[(hh*12 + s)*66 + pl];
            float m = a[0];
#pragma unroll
            for (int s = 1; s < 12; ++s) m = fmaxf(m, a[s]);
            float sum = 0.f;
#pragma unroll
            for (int s = 0; s < 12; ++s) { a[s] = __expf(a[s]-m); sum += a[s]; }
            const float inv = 1.f/sum;
            float4* ma = (float4*)(metaA + ((size_t)(b*NH_ + hh)*P_ + p)*12);
#pragma unroll
            for (int i = 0; i < 3; ++i)
                ma[i] = make_float4(a[4*i]*inv, a[4*i+1]*inv, a[4*i+2]*inv, a[4*i+3]*inv);
        }
    }
}

// ---------------------------------------------------------------------------
// bilinear sampling + attention-weighted sum (unchanged)
__global__ __launch_bounds__(256) void k_sample(
    const float* __restrict__ v_ws, const float* __restrict__ metaP,
    const float* __restrict__ metaA, float* __restrict__ out_pre)
{
    const int tid = threadIdx.x;
    const int u  = tid >> 2;
    const int c4 = tid & 3;
    const int p  = blockIdx.x*64 + u;
    const int hh = blockIdx.y, b = blockIdx.z;

    const size_t mbase = (size_t)(b*NH_ + hh)*P_ + p;
    const float4* mp4 = (const float4*)(metaP + mbase*24);
    const float4* ma4 = (const float4*)(metaA + mbase*12);

    float pxv[12], pyv[12], av[12];
#pragma unroll
    for (int i = 0; i < 6; ++i) {
        float4 m = mp4[i];
        pxv[i*2]   = m.x; pyv[i*2]   = m.y;
        pxv[i*2+1] = m.z; pyv[i*2+1] = m.w;
    }
#pragma unroll
    for (int i = 0; i < 3; ++i) {
        float4 m = ma4[i];
        av[i*4]=m.x; av[i*4+1]=m.y; av[i*4+2]=m.z; av[i*4+3]=m.w;
    }

    float ax=0.f, ay=0.f, az=0.f, aw=0.f;
#pragma unroll
    for (int l = 0; l < NL_; ++l) {
        const float4* vb = (const float4*)(v_ws + ((size_t)(b*NL_ + l)*P_)*C_ + hh*HD_ + c4*4);
#pragma unroll
        for (int pt = 0; pt < NP_; ++pt) {
            const int s = l*4 + pt;
            float px = fminf(fmaxf(pxv[s], 0.f), (float)(W_-1));
            float py = fminf(fmaxf(pyv[s], 0.f), (float)(H_-1));
            float x0f = floorf(px), y0f = floorf(py);
            float wx = px - x0f, wy = py - y0f;
            int x0 = (int)x0f, y0 = (int)y0f;
            int x1 = min(x0+1, W_-1), y1 = min(y0+1, H_-1);
            const float4* r0 = vb + (size_t)(y0*W_)*32;
            const float4* r1 = vb + (size_t)(y1*W_)*32;
            float4 v00 = r0[(size_t)x0*32], v01 = r0[(size_t)x1*32];
            float4 v10 = r1[(size_t)x0*32], v11 = r1[(size_t)x1*32];
            float tx, bx2, val;
            float a = av[s];
            tx = v00.x + (v01.x - v00.x)*wx; bx2 = v10.x + (v11.x - v10.x)*wx;
            val = tx + (bx2 - tx)*wy;  ax = fmaf(a, val, ax);
            tx = v00.y + (v01.y - v00.y)*wx; bx2 = v10.y + (v11.y - v10.y)*wx;
            val = tx + (bx2 - tx)*wy;  ay = fmaf(a, val, ay);
            tx = v00.z + (v01.z - v00.z)*wx; bx2 = v10.z + (v11.z - v10.z)*wx;
            val = tx + (bx2 - tx)*wy;  az = fmaf(a, val, az);
            tx = v00.w + (v01.w - v00.w)*wx; bx2 = v10.w + (v11.w - v10.w)*wx;
            val = tx + (bx2 - tx)*wy;  aw = fmaf(a, val, aw);
        }
    }
    float4* op = (float4*)(out_pre + ((size_t)b*P_ + p)*C_ + hh*HD_ + c4*4);
    *op = make_float4(ax, ay, az, aw);
}

// ---------------------------------------------------------------------------
// MFMA final conv: out[b][oc][p] = op_w . out_pre[b][p][:] + op_b
__global__ __launch_bounds__(256) void k_convout(
    const float* __restrict__ inp, const float* __restrict__ op_w,
    const float* __restrict__ op_b, float* __restrict__ out)
{
    const int tid = threadIdx.x;
    const int wv = tid >> 6, l = tid & 63;
    const int lr = l & 15, lg = l >> 4;
    const int b = blockIdx.y;
    const int px0 = blockIdx.x * 64;

    bf16x8 Ahi[2][4], Alo[2][4];
#pragma unroll
    for (int rt = 0; rt < 2; ++rt)
#pragma unroll
        for (int t = 0; t < 4; ++t) {
            const float* wr = op_w + (size_t)(wv*32 + rt*16 + lr)*128 + t*32 + lg*8;
            float x8[8];
            float4 a = *(const float4*)wr, bb = *(const float4*)(wr + 4);
            x8[0]=a.x; x8[1]=a.y; x8[2]=a.z; x8[3]=a.w;
            x8[4]=bb.x; x8[5]=bb.y; x8[6]=bb.z; x8[7]=bb.w;
            cvt8(x8, Ahi[rt][t], Alo[rt][t]);
        }

    f32x4 acc[2][4];
#pragma unroll
    for (int rt = 0; rt < 2; ++rt)
#pragma unroll
        for (int c = 0; c < 4; ++c)
#pragma unroll
            for (int r = 0; r < 4; ++r) acc[rt][c][r] = 0.f;

#pragma unroll
    for (int c = 0; c < 4; ++c) {
        const int px = px0 + c*16 + lr;
        const float* xb = inp + ((size_t)b*P_ + px)*C_;
#pragma unroll
        for (int t = 0; t < 4; ++t) {
            const float* xp = xb + t*32 + lg*8;
            float x8[8];
            float4 a = *(const float4*)xp, bb = *(const float4*)(xp + 4);
            x8[0]=a.x; x8[1]=a.y; x8[2]=a.z; x8[3]=a.w;
            x8[4]=bb.x; x8[5]=bb.y; x8[6]=bb.z; x8[7]=bb.w;
            bf16x8 bhi, blo; cvt8(x8, bhi, blo);
#pragma unroll
            for (int rt = 0; rt < 2; ++rt) {
                acc[rt][c] = MFMA16(Ahi[rt][t], bhi, acc[rt][c]);
                acc[rt][c] = MFMA16(Alo[rt][t], bhi, acc[rt][c]);
                acc[rt][c] = MFMA16(Ahi[rt][t], blo, acc[rt][c]);
            }
        }
    }

    float* ob = out + (size_t)b*C_*P_;
#pragma unroll
    for (int rt = 0; rt < 2; ++rt)
#pragma unroll
        for (int c = 0; c < 4; ++c) {
            const int px = px0 + c*16 + lr;
#pragma unroll
            for (int r = 0; r < 4; ++r) {
                const int oc = wv*32 + rt*16 + lg*4 + r;
                ob[(size_t)oc*P_ + px] = acc[rt][c][r] + op_b[oc];
            }
        }
}

// ---------------------------------------------------------------------------
extern "C" void kernel_launch(void* const* d_in, const int* in_sizes, int n_in,
                              void* d_out, int out_size, void* d_ws, size_t ws_size,
                              hipStream_t stream)
{
    const float* query = (const float*)d_in[0];
    // d_in[1] = keys : UNUSED by reference
    const float* values = (const float*)d_in[2];
    const float* so_w1 = (const float*)d_in[3];
    const float* so_b1 = (const float*)d_in[4];
    const float* so_g  = (const float*)d_in[5];
    const float* so_be = (const float*)d_in[6];
    const float* so_w2 = (const float*)d_in[7];
    const float* so_b2 = (const float*)d_in[8];
    const float* aw_w1 = (const float*)d_in[9];
    const float* aw_b1 = (const float*)d_in[10];
    const float* aw_g  = (const float*)d_in[11];
    const float* aw_be = (const float*)d_in[12];
    const float* aw_w2 = (const float*)d_in[13];
    const float* aw_b2 = (const float*)d_in[14];
    const float* vp_w  = (const float*)d_in[15];
    const float* vp_b  = (const float*)d_in[16];
    const float* op_w  = (const float*)d_in[17];
    const float* op_b  = (const float*)d_in[18];
    const float* le    = (const float*)d_in[19];

    float* ws      = (float*)d_ws;
    float* v_ws    = ws + OFF_V;
    float* hid     = ws + OFF_HID;
    float* metaP   = ws + OFF_MP;
    float* metaA   = ws + OFF_MA;
    float* stats   = ws + OFF_ST;
    float* be      = ws + OFF_BE;
    float* out_pre = hid;                 // hid dead after k_conv2 -> reuse
    float* out     = (float*)d_out;

    k_prep<<<dim3(1), dim3(384), 0, stream>>>(vp_w, vp_b, le, be, stats);
    k_vproj<<<dim3(P_/64, B_*NL_), dim3(256), 0, stream>>>(values, vp_w, be, v_ws);
    k_conv1<<<dim3(P_/64, B_), dim3(256), 0, stream>>>(query, so_w1, so_b1, aw_w1, aw_b1, hid, stats);
    k_conv2<<<dim3(P_/64, B_), dim3(256), 0, stream>>>(hid, stats, so_g, so_be, aw_g, aw_be,
                                                       so_w2, so_b2, aw_w2, aw_b2, metaP, metaA);
    k_sample<<<dim3(P_/64, NH_, B_), dim3(256), 0, stream>>>(v_ws, metaP, metaA, out_pre);
    k_convout<<<dim3(P_/64, B_), dim3(256), 0, stream>>>(out_pre, op_w, op_b, out);
}

// Round 4
// 276.983 us; speedup vs baseline: 5.6643x; 1.3134x over previous
//
#include <hip/hip_runtime.h>
#include <cstdint>
#include <cstddef>

#define B_ 4
#define C_ 128
#define H_ 128
#define W_ 128
#define P_ (H_*W_)       // 16384
#define NH_ 8
#define NL_ 3
#define NP_ 4
#define HD_ 16
#define C2_ 64

// ---- workspace layout (float elements) ----
#define SZ_V      ((size_t)B_*NL_*P_*C_)          // region reserved; v stored as bf16 [b][l][h][p][hd]
#define OFF_V     ((size_t)0)
#define OFF_HID   (OFF_V + SZ_V)                   // hid [br][b][c][p], later reused as out_pre [b][p][c]
#define SZ_HID    ((size_t)2*B_*C2_*P_)
#define OFF_MP    (OFF_HID + SZ_HID)               // metaP [b][h][p][24]
#define SZ_MP     ((size_t)B_*NH_*P_*24)
#define OFF_MA    (OFF_MP + SZ_MP)                 // metaA [b][h][p][12]
#define SZ_MA     ((size_t)B_*NH_*P_*12)
#define OFF_ST    (OFF_MA + SZ_MA)                 // GN stats [br][b][g][2]
#define SZ_ST     ((size_t)128)
#define OFF_BE    (OFF_ST + SZ_ST)                 // vp effective bias [l][128]
#define SZ_BE     ((size_t)(NL_*C_))

typedef short bf16x8 __attribute__((ext_vector_type(8)));
typedef float f32x4  __attribute__((ext_vector_type(4)));
#define MFMA16(a,b,c) __builtin_amdgcn_mfma_f32_16x16x32_bf16(a,b,c,0,0,0)

// split fp32 -> bf16 hi + bf16 lo (truncation; rem exact; total rel err ~2^-16)
__device__ __forceinline__ void cvt8(const float* __restrict__ x, bf16x8& hi, bf16x8& lo) {
#pragma unroll
    for (int j = 0; j < 8; ++j) {
        unsigned ub = __float_as_uint(x[j]);
        hi[j] = (short)(ub >> 16);
        float rem = x[j] - __uint_as_float(ub & 0xffff0000u);
        lo[j] = (short)(__float_as_uint(rem) >> 16);
    }
}

__device__ __forceinline__ unsigned short f2bf_rn(float f) {
    unsigned u = __float_as_uint(f);
    return (unsigned short)((u + 0x7fffu + ((u >> 16) & 1u)) >> 16);
}
__device__ __forceinline__ float bflo(unsigned u) { return __uint_as_float(u << 16); }
__device__ __forceinline__ float bfhi(unsigned u) { return __uint_as_float(u & 0xffff0000u); }

// ---------------------------------------------------------------------------
// prep: zero GN stats; fold level_embed into vp bias
__global__ void k_prep(const float* __restrict__ vp_w, const float* __restrict__ vp_b,
                       const float* __restrict__ le, float* __restrict__ bias_eff,
                       float* __restrict__ stats)
{
    const int t = threadIdx.x;            // 384 threads
    if (t < 128) stats[t] = 0.f;
    const int l = t >> 7;
    const int o = t & 127;
    float d = vp_b[o];
    for (int k = 0; k < 128; ++k) d = fmaf(vp_w[o*128 + k], le[l*128 + k], d);
    bias_eff[l*128 + o] = d;
}

// ---------------------------------------------------------------------------
// MFMA value projection -> bf16 head-planar v [b][l][h][p][hd]
__global__ __launch_bounds__(256) void k_vproj(
    const float* __restrict__ vals, const float* __restrict__ vp_w,
    const float* __restrict__ bias_eff, unsigned short* __restrict__ v16)
{
    const int tid = threadIdx.x;
    const int wv = tid >> 6, l = tid & 63;
    const int lr = l & 15, lg = l >> 4;
    const int bl = blockIdx.y, lvl = bl % NL_;
    const int px0 = blockIdx.x * 64;
    const float* __restrict__ X = vals + (size_t)bl*C_*P_;

    // A fragments: rows oc = wv*32 + rt*16 + lr ; k = t*32 + lg*8 + j
    bf16x8 Ahi[2][4], Alo[2][4];
#pragma unroll
    for (int rt = 0; rt < 2; ++rt)
#pragma unroll
        for (int t = 0; t < 4; ++t) {
            const float* wr = vp_w + (size_t)(wv*32 + rt*16 + lr)*128 + t*32 + lg*8;
            float x8[8];
            float4 a = *(const float4*)wr, b = *(const float4*)(wr + 4);
            x8[0]=a.x; x8[1]=a.y; x8[2]=a.z; x8[3]=a.w;
            x8[4]=b.x; x8[5]=b.y; x8[6]=b.z; x8[7]=b.w;
            cvt8(x8, Ahi[rt][t], Alo[rt][t]);
        }

    f32x4 acc[2][4];
#pragma unroll
    for (int rt = 0; rt < 2; ++rt)
#pragma unroll
        for (int c = 0; c < 4; ++c)
#pragma unroll
            for (int r = 0; r < 4; ++r) acc[rt][c][r] = 0.f;

    // flattened (c,t) steps with 1-step prefetch
    float xb[2][8];
#pragma unroll
    for (int j = 0; j < 8; ++j)
        xb[0][j] = X[(size_t)(0*32 + lg*8 + j)*P_ + px0 + 0*16 + lr];
#pragma unroll
    for (int s = 0; s < 16; ++s) {
        const int c = s >> 2, t = s & 3;
        if (s < 15) {
            const int cn = (s+1) >> 2, tn = (s+1) & 3;
            const float* xp = X + (size_t)(tn*32 + lg*8)*P_ + px0 + cn*16 + lr;
#pragma unroll
            for (int j = 0; j < 8; ++j) xb[(s+1)&1][j] = xp[(size_t)j*P_];
        }
        bf16x8 bhi, blo; cvt8(xb[s&1], bhi, blo);
#pragma unroll
        for (int rt = 0; rt < 2; ++rt) {
            acc[rt][c] = MFMA16(Ahi[rt][t], bhi, acc[rt][c]);
            acc[rt][c] = MFMA16(Alo[rt][t], bhi, acc[rt][c]);
            acc[rt][c] = MFMA16(Ahi[rt][t], blo, acc[rt][c]);
        }
    }

    const float* be = bias_eff + lvl*128;
#pragma unroll
    for (int c = 0; c < 4; ++c) {
        const int px = px0 + c*16 + lr;
#pragma unroll
        for (int rt = 0; rt < 2; ++rt) {
            const int h  = wv*2 + rt;
            const int oc = h*16 + lg*4;
            uint2 st;
            st.x = (unsigned)f2bf_rn(acc[rt][c][0] + be[oc+0])
                 | ((unsigned)f2bf_rn(acc[rt][c][1] + be[oc+1]) << 16);
            st.y = (unsigned)f2bf_rn(acc[rt][c][2] + be[oc+2])
                 | ((unsigned)f2bf_rn(acc[rt][c][3] + be[oc+3]) << 16);
            *(uint2*)(v16 + (((size_t)bl*NH_ + h)*P_ + px)*16 + lg*4) = st;
        }
    }
}

// ---------------------------------------------------------------------------
// MFMA conv1 (both branches via waves): hid = W1*query + b1 (channel-major) + GN stats
__global__ __launch_bounds__(256) void k_conv1(
    const float* __restrict__ q,
    const float* __restrict__ w_so, const float* __restrict__ b_so,
    const float* __restrict__ w_aw, const float* __restrict__ b_aw,
    float* __restrict__ hid, float* __restrict__ stats)
{
    const int tid = threadIdx.x;
    const int wv = tid >> 6, l = tid & 63;
    const int lr = l & 15, lg = l >> 4;
    const int b = blockIdx.y;
    const int br = wv >> 1, oc0 = (wv & 1) * 32;
    const float* __restrict__ W  = br ? w_aw : w_so;
    const float* __restrict__ bi = br ? b_aw : b_so;
    const float* __restrict__ X  = q + (size_t)b*C_*P_;
    const int px0 = blockIdx.x * 64;

    bf16x8 Ahi[2][4], Alo[2][4];
#pragma unroll
    for (int rt = 0; rt < 2; ++rt)
#pragma unroll
        for (int t = 0; t < 4; ++t) {
            const float* wr = W + (size_t)(oc0 + rt*16 + lr)*128 + t*32 + lg*8;
            float x8[8];
            float4 a = *(const float4*)wr, bb = *(const float4*)(wr + 4);
            x8[0]=a.x; x8[1]=a.y; x8[2]=a.z; x8[3]=a.w;
            x8[4]=bb.x; x8[5]=bb.y; x8[6]=bb.z; x8[7]=bb.w;
            cvt8(x8, Ahi[rt][t], Alo[rt][t]);
        }

    f32x4 acc[2][4];
#pragma unroll
    for (int rt = 0; rt < 2; ++rt)
#pragma unroll
        for (int c = 0; c < 4; ++c)
#pragma unroll
            for (int r = 0; r < 4; ++r) acc[rt][c][r] = 0.f;

    float xb[2][8];
#pragma unroll
    for (int j = 0; j < 8; ++j)
        xb[0][j] = X[(size_t)(0*32 + lg*8 + j)*P_ + px0 + 0*16 + lr];
#pragma unroll
    for (int s = 0; s < 16; ++s) {
        const int c = s >> 2, t = s & 3;
        if (s < 15) {
            const int cn = (s+1) >> 2, tn = (s+1) & 3;
            const float* xp = X + (size_t)(tn*32 + lg*8)*P_ + px0 + cn*16 + lr;
#pragma unroll
            for (int j = 0; j < 8; ++j) xb[(s+1)&1][j] = xp[(size_t)j*P_];
        }
        bf16x8 bhi, blo; cvt8(xb[s&1], bhi, blo);
#pragma unroll
        for (int rt = 0; rt < 2; ++rt) {
            acc[rt][c] = MFMA16(Ahi[rt][t], bhi, acc[rt][c]);
            acc[rt][c] = MFMA16(Alo[rt][t], bhi, acc[rt][c]);
            acc[rt][c] = MFMA16(Ahi[rt][t], blo, acc[rt][c]);
        }
    }

    float* hb = hid + ((size_t)(br*B_ + b)*C2_)*P_;
#pragma unroll
    for (int rt = 0; rt < 2; ++rt) {
        float s = 0.f, ss = 0.f;
#pragma unroll
        for (int c = 0; c < 4; ++c) {
            const int px = px0 + c*16 + lr;
#pragma unroll
            for (int r = 0; r < 4; ++r) {
                const int oc = oc0 + rt*16 + lg*4 + r;
                float v = acc[rt][c][r] + bi[oc];
                hb[(size_t)oc*P_ + px] = v;
                s += v; ss += v*v;
            }
        }
#pragma unroll
        for (int off = 16; off > 0; off >>= 1) {
            s  += __shfl_xor(s,  off, 64);
            ss += __shfl_xor(ss, off, 64);
        }
        if ((l & 31) == 0) {
            const int g = (oc0 + rt*16 + (l >> 4)*4) >> 3;
            atomicAdd(&stats[((br*B_ + b)*8 + g)*2 + 0], s);
            atomicAdd(&stats[((br*B_ + b)*8 + g)*2 + 1], ss);
        }
    }
}

// ---------------------------------------------------------------------------
// MFMA conv2 + meta: GN+ReLU on B-operand, 2-phase LDS, fused post-processing.
__global__ __launch_bounds__(256) void k_conv2(
    const float* __restrict__ hid, const float* __restrict__ stats,
    const float* __restrict__ so_g, const float* __restrict__ so_be,
    const float* __restrict__ aw_g, const float* __restrict__ aw_be,
    const float* __restrict__ so_w2, const float* __restrict__ so_b2,
    const float* __restrict__ aw_w2, const float* __restrict__ aw_b2,
    float* __restrict__ metaP, float* __restrict__ metaA)
{
    __shared__ float sc[2][64], sh[2][64];
    __shared__ float S[192*66];
    const int tid = threadIdx.x;
    const int wv = tid >> 6, l = tid & 63;
    const int lr = l & 15, lg = l >> 4;
    const int b = blockIdx.y;
    const int px0 = blockIdx.x * 64;

    if (tid < 128) {
        const int br = tid >> 6, c = tid & 63, g = c >> 3;
        const float ninv = 1.f/(8.f*(float)P_);
        float s  = stats[((br*B_ + b)*8 + g)*2 + 0];
        float ss = stats[((br*B_ + b)*8 + g)*2 + 1];
        float mu  = s*ninv;
        float var = ss*ninv - mu*mu;
        float rs  = rsqrtf(var + 1e-5f);
        float ga = br ? aw_g[c]  : so_g[c];
        float be = br ? aw_be[c] : so_be[c];
        sc[br][c] = ga*rs;
        sh[br][c] = be - mu*ga*rs;
    }
    __syncthreads();

    const int pxw = px0 + wv*16 + lr;

    bf16x8 Bhi[2], Blo[2];
    {
        const float* hs = hid + ((size_t)(0*B_ + b)*C2_)*P_ + pxw;
#pragma unroll
        for (int t = 0; t < 2; ++t) {
            float x8[8];
#pragma unroll
            for (int j = 0; j < 8; ++j) {
                const int k = t*32 + lg*8 + j;
                x8[j] = fmaxf(fmaf(hs[(size_t)k*P_], sc[0][k], sh[0][k]), 0.f);
            }
            cvt8(x8, Bhi[t], Blo[t]);
        }
    }
#pragma unroll
    for (int tile = 0; tile < 12; ++tile) {
        f32x4 acc; acc[0]=0.f; acc[1]=0.f; acc[2]=0.f; acc[3]=0.f;
#pragma unroll
        for (int t = 0; t < 2; ++t) {
            const float* wr = so_w2 + (size_t)(tile*16 + lr)*64 + t*32 + lg*8;
            float x8[8];
            float4 a = *(const float4*)wr, bb = *(const float4*)(wr + 4);
            x8[0]=a.x; x8[1]=a.y; x8[2]=a.z; x8[3]=a.w;
            x8[4]=bb.x; x8[5]=bb.y; x8[6]=bb.z; x8[7]=bb.w;
            bf16x8 ahi, alo; cvt8(x8, ahi, alo);
            acc = MFMA16(ahi, Bhi[t], acc);
            acc = MFMA16(alo, Bhi[t], acc);
            acc = MFMA16(ahi, Blo[t], acc);
        }
#pragma unroll
        for (int r = 0; r < 4; ++r) {
            const int ch = tile*16 + lg*4 + r;
            S[ch*66 + wv*16 + lr] = acc[r] + so_b2[ch];
        }
    }
    __syncthreads();

    {
        const int pl = tid & 63, sub = tid >> 6;
        const int p = px0 + pl;
        const int x = p & (W_-1), y = p >> 7;
        const float refx = (float)x * (1.f/(float)(W_-1));
        const float refy = (float)y * (1.f/(float)(H_-1));
#pragma unroll
        for (int hi = 0; hi < 2; ++hi) {
            const int hh = sub*2 + hi;
            float2 buf[12];
#pragma unroll
            for (int s = 0; s < 12; ++s) {
                float ox = S[(hh*24 + 2*s    )*66 + pl];
                float oy = S[(hh*24 + 2*s + 1)*66 + pl];
                float lx = fminf(fmaxf(refx + ox*(1.f/(float)W_), 0.f), 1.f);
                float ly = fminf(fmaxf(refy + oy*(1.f/(float)H_), 0.f), 1.f);
                buf[s] = make_float2(lx*(float)W_ - 0.5f, ly*(float)H_ - 0.5f);
            }
            float4* mp = (float4*)(metaP + ((size_t)(b*NH_ + hh)*P_ + p)*24);
#pragma unroll
            for (int i = 0; i < 6; ++i)
                mp[i] = make_float4(buf[2*i].x, buf[2*i].y, buf[2*i+1].x, buf[2*i+1].y);
        }
    }
    __syncthreads();

    {
        const float* hs = hid + ((size_t)(1*B_ + b)*C2_)*P_ + pxw;
#pragma unroll
        for (int t = 0; t < 2; ++t) {
            float x8[8];
#pragma unroll
            for (int j = 0; j < 8; ++j) {
                const int k = t*32 + lg*8 + j;
                x8[j] = fmaxf(fmaf(hs[(size_t)k*P_], sc[1][k], sh[1][k]), 0.f);
            }
            cvt8(x8, Bhi[t], Blo[t]);
        }
    }
#pragma unroll
    for (int tile = 0; tile < 6; ++tile) {
        f32x4 acc; acc[0]=0.f; acc[1]=0.f; acc[2]=0.f; acc[3]=0.f;
#pragma unroll
        for (int t = 0; t < 2; ++t) {
            const float* wr = aw_w2 + (size_t)(tile*16 + lr)*64 + t*32 + lg*8;
            float x8[8];
            float4 a = *(const float4*)wr, bb = *(const float4*)(wr + 4);
            x8[0]=a.x; x8[1]=a.y; x8[2]=a.z; x8[3]=a.w;
            x8[4]=bb.x; x8[5]=bb.y; x8[6]=bb.z; x8[7]=bb.w;
            bf16x8 ahi, alo; cvt8(x8, ahi, alo);
            acc = MFMA16(ahi, Bhi[t], acc);
            acc = MFMA16(alo, Bhi[t], acc);
            acc = MFMA16(ahi, Blo[t], acc);
        }
#pragma unroll
        for (int r = 0; r < 4; ++r) {
            const int ch = tile*16 + lg*4 + r;
            S[ch*66 + wv*16 + lr] = acc[r] + aw_b2[ch];
        }
    }
    __syncthreads();

    {
        const int pl = tid & 63, sub = tid >> 6;
        const int p = px0 + pl;
#pragma unroll
        for (int hi = 0; hi < 2; ++hi) {
            const int hh = sub*2 + hi;
            float a[12];
#pragma unroll
            for (int s = 0; s < 12; ++s) a[s] = S[(hh*12 + s)*66 + pl];
            float m = a[0];
#pragma unroll
            for (int s = 1; s < 12; ++s) m = fmaxf(m, a[s]);
            float sum = 0.f;
#pragma unroll
            for (int s = 0; s < 12; ++s) { a[s] = __expf(a[s]-m); sum += a[s]; }
            const float inv = 1.f/sum;
            float4* ma = (float4*)(metaA + ((size_t)(b*NH_ + hh)*P_ + p)*12);
#pragma unroll
            for (int i = 0; i < 3; ++i)
                ma[i] = make_float4(a[4*i]*inv, a[4*i+1]*inv, a[4*i+2]*inv, a[4*i+3]*inv);
        }
    }
}

// ---------------------------------------------------------------------------
// bilinear sampling + attention-weighted sum. bf16 head-planar v.
// block = 256 threads = 128 (pixel,head) units x 2 lanes (8 channels each)
__global__ __launch_bounds__(256) void k_sample(
    const unsigned short* __restrict__ v16, const float* __restrict__ metaP,
    const float* __restrict__ metaA, float* __restrict__ out_pre)
{
    const int tid = threadIdx.x;
    const int u  = tid >> 1;
    const int c8 = tid & 1;
    const int p  = blockIdx.x*128 + u;
    const int hh = blockIdx.y, b = blockIdx.z;

    const size_t mbase = (size_t)(b*NH_ + hh)*P_ + p;
    const float4* mp4 = (const float4*)(metaP + mbase*24);
    const float4* ma4 = (const float4*)(metaA + mbase*12);

    float pxv[12], pyv[12], av[12];
#pragma unroll
    for (int i = 0; i < 6; ++i) {
        float4 m = mp4[i];
        pxv[i*2]   = m.x; pyv[i*2]   = m.y;
        pxv[i*2+1] = m.z; pyv[i*2+1] = m.w;
    }
#pragma unroll
    for (int i = 0; i < 3; ++i) {
        float4 m = ma4[i];
        av[i*4]=m.x; av[i*4+1]=m.y; av[i*4+2]=m.z; av[i*4+3]=m.w;
    }

    float acc[8];
#pragma unroll
    for (int j = 0; j < 8; ++j) acc[j] = 0.f;

#pragma unroll
    for (int l = 0; l < NL_; ++l) {
        const unsigned short* vb = v16 + (((size_t)(b*NL_ + l)*NH_ + hh)*P_)*16 + c8*8;
#pragma unroll
        for (int pt = 0; pt < NP_; ++pt) {
            const int s = l*4 + pt;
            float px = fminf(fmaxf(pxv[s], 0.f), (float)(W_-1));
            float py = fminf(fmaxf(pyv[s], 0.f), (float)(H_-1));
            float x0f = floorf(px), y0f = floorf(py);
            float wx = px - x0f, wy = py - y0f;
            int x0 = (int)x0f, y0 = (int)y0f;
            int x1 = min(x0+1, W_-1), y1 = min(y0+1, H_-1);
            uint4 q00 = *(const uint4*)(vb + (size_t)(y0*W_ + x0)*16);
            uint4 q01 = *(const uint4*)(vb + (size_t)(y0*W_ + x1)*16);
            uint4 q10 = *(const uint4*)(vb + (size_t)(y1*W_ + x0)*16);
            uint4 q11 = *(const uint4*)(vb + (size_t)(y1*W_ + x1)*16);
            const float a = av[s];
            const float a11 = a*wx*wy;
            const float a10 = a*wy - a11;
            const float a01 = a*wx - a11;
            const float a00 = a - a01 - a10 - a11;
            const unsigned* u00 = (const unsigned*)&q00;
            const unsigned* u01 = (const unsigned*)&q01;
            const unsigned* u10 = (const unsigned*)&q10;
            const unsigned* u11 = (const unsigned*)&q11;
#pragma unroll
            for (int i = 0; i < 4; ++i) {
                float r;
                r = acc[2*i];
                r = fmaf(a00, bflo(u00[i]), r);
                r = fmaf(a01, bflo(u01[i]), r);
                r = fmaf(a10, bflo(u10[i]), r);
                r = fmaf(a11, bflo(u11[i]), r);
                acc[2*i] = r;
                r = acc[2*i+1];
                r = fmaf(a00, bfhi(u00[i]), r);
                r = fmaf(a01, bfhi(u01[i]), r);
                r = fmaf(a10, bfhi(u10[i]), r);
                r = fmaf(a11, bfhi(u11[i]), r);
                acc[2*i+1] = r;
            }
        }
    }
    float* op = out_pre + ((size_t)b*P_ + p)*C_ + hh*HD_ + c8*8;
    *(float4*)op       = make_float4(acc[0], acc[1], acc[2], acc[3]);
    *(float4*)(op + 4) = make_float4(acc[4], acc[5], acc[6], acc[7]);
}

// ---------------------------------------------------------------------------
// MFMA final conv: out[b][oc][p] = op_w . out_pre[b][p][:] + op_b
__global__ __launch_bounds__(256) void k_convout(
    const float* __restrict__ inp, const float* __restrict__ op_w,
    const float* __restrict__ op_b, float* __restrict__ out)
{
    const int tid = threadIdx.x;
    const int wv = tid >> 6, l = tid & 63;
    const int lr = l & 15, lg = l >> 4;
    const int b = blockIdx.y;
    const int px0 = blockIdx.x * 64;

    bf16x8 Ahi[2][4], Alo[2][4];
#pragma unroll
    for (int rt = 0; rt < 2; ++rt)
#pragma unroll
        for (int t = 0; t < 4; ++t) {
            const float* wr = op_w + (size_t)(wv*32 + rt*16 + lr)*128 + t*32 + lg*8;
            float x8[8];
            float4 a = *(const float4*)wr, bb = *(const float4*)(wr + 4);
            x8[0]=a.x; x8[1]=a.y; x8[2]=a.z; x8[3]=a.w;
            x8[4]=bb.x; x8[5]=bb.y; x8[6]=bb.z; x8[7]=bb.w;
            cvt8(x8, Ahi[rt][t], Alo[rt][t]);
        }

    f32x4 acc[2][4];
#pragma unroll
    for (int rt = 0; rt < 2; ++rt)
#pragma unroll
        for (int c = 0; c < 4; ++c)
#pragma unroll
            for (int r = 0; r < 4; ++r) acc[rt][c][r] = 0.f;

#pragma unroll
    for (int c = 0; c < 4; ++c) {
        const int px = px0 + c*16 + lr;
        const float* xb = inp + ((size_t)b*P_ + px)*C_;
#pragma unroll
        for (int t = 0; t < 4; ++t) {
            const float* xp = xb + t*32 + lg*8;
            float x8[8];
            float4 a = *(const float4*)xp, bb = *(const float4*)(xp + 4);
            x8[0]=a.x; x8[1]=a.y; x8[2]=a.z; x8[3]=a.w;
            x8[4]=bb.x; x8[5]=bb.y; x8[6]=bb.z; x8[7]=bb.w;
            bf16x8 bhi, blo; cvt8(x8, bhi, blo);
#pragma unroll
            for (int rt = 0; rt < 2; ++rt) {
                acc[rt][c] = MFMA16(Ahi[rt][t], bhi, acc[rt][c]);
                acc[rt][c] = MFMA16(Alo[rt][t], bhi, acc[rt][c]);
                acc[rt][c] = MFMA16(Ahi[rt][t], blo, acc[rt][c]);
            }
        }
    }

    float* ob = out + (size_t)b*C_*P_;
#pragma unroll
    for (int rt = 0; rt < 2; ++rt)
#pragma unroll
        for (int c = 0; c < 4; ++c) {
            const int px = px0 + c*16 + lr;
#pragma unroll
            for (int r = 0; r < 4; ++r) {
                const int oc = wv*32 + rt*16 + lg*4 + r;
                ob[(size_t)oc*P_ + px] = acc[rt][c][r] + op_b[oc];
            }
        }
}

// ---------------------------------------------------------------------------
extern "C" void kernel_launch(void* const* d_in, const int* in_sizes, int n_in,
                              void* d_out, int out_size, void* d_ws, size_t ws_size,
                              hipStream_t stream)
{
    const float* query = (const float*)d_in[0];
    // d_in[1] = keys : UNUSED by reference
    const float* values = (const float*)d_in[2];
    const float* so_w1 = (const float*)d_in[3];
    const float* so_b1 = (const float*)d_in[4];
    const float* so_g  = (const float*)d_in[5];
    const float* so_be = (const float*)d_in[6];
    const float* so_w2 = (const float*)d_in[7];
    const float* so_b2 = (const float*)d_in[8];
    const float* aw_w1 = (const float*)d_in[9];
    const float* aw_b1 = (const float*)d_in[10];
    const float* aw_g  = (const float*)d_in[11];
    const float* aw_be = (const float*)d_in[12];
    const float* aw_w2 = (const float*)d_in[13];
    const float* aw_b2 = (const float*)d_in[14];
    const float* vp_w  = (const float*)d_in[15];
    const float* vp_b  = (const float*)d_in[16];
    const float* op_w  = (const float*)d_in[17];
    const float* op_b  = (const float*)d_in[18];
    const float* le    = (const float*)d_in[19];

    float* ws      = (float*)d_ws;
    unsigned short* v16 = (unsigned short*)(ws + OFF_V);
    float* hid     = ws + OFF_HID;
    float* metaP   = ws + OFF_MP;
    float* metaA   = ws + OFF_MA;
    float* stats   = ws + OFF_ST;
    float* be      = ws + OFF_BE;
    float* out_pre = hid;                 // hid dead after k_conv2 -> reuse
    float* out     = (float*)d_out;

    k_prep<<<dim3(1), dim3(384), 0, stream>>>(vp_w, vp_b, le, be, stats);
    k_vproj<<<dim3(P_/64, B_*NL_), dim3(256), 0, stream>>>(values, vp_w, be, v16);
    k_conv1<<<dim3(P_/64, B_), dim3(256), 0, stream>>>(query, so_w1, so_b1, aw_w1, aw_b1, hid, stats);
    k_conv2<<<dim3(P_/64, B_), dim3(256), 0, stream>>>(hid, stats, so_g, so_be, aw_g, aw_be,
                                                       so_w2, so_b2, aw_w2, aw_b2, metaP, metaA);
    k_sample<<<dim3(P_/128, NH_, B_), dim3(256), 0, stream>>>(v16, metaP, metaA, out_pre);
    k_convout<<<dim3(P_/64, B_), dim3(256), 0, stream>>>(out_pre, op_w, op_b, out);
}